// Round 2
// baseline (1363.167 us; speedup 1.0000x reference)
//
#include <hip/hip_runtime.h>

typedef unsigned short u16;
typedef short bf16x8 __attribute__((ext_vector_type(8)));
typedef float f32x4 __attribute__((ext_vector_type(4)));

#define EPSV 1e-3f

__device__ __forceinline__ float bf2f(u16 u) {
  union { unsigned int i; float f; } x; x.i = ((unsigned int)u) << 16; return x.f;
}
__device__ __forceinline__ u16 f2bf(float f) {
  union { float f; unsigned int i; } x; x.f = f;
  unsigned int r = x.i + 0x7fffu + ((x.i >> 16) & 1u);   // RNE
  return (u16)(r >> 16);
}

// ---------------------------------------------------------------------------
// Weight transform: fw (2,64,128,3,3) f32 -> fwT [set][ky*3+kx][co][ci] bf16
// ---------------------------------------------------------------------------
__global__ void twt_kernel(const float* __restrict__ fw, u16* __restrict__ fwT) {
  int i = blockIdx.x * blockDim.x + threadIdx.x;
  if (i >= 2 * 9 * 64 * 128) return;
  int ci = i & 127;
  int r = i >> 7;
  int co = r & 63; r >>= 6;
  int kyx = r % 9;
  int set = r / 9;
  fwT[i] = f2bf(fw[(((set * 64 + co) * 128 + ci) * 9) + kyx]);
}

// ---------------------------------------------------------------------------
// VFE: per-voxel 2-layer MLP + masked max-pool. One wave per voxel (block=64).
// lane = output channel. Layer2 folds gmax-concat into a per-channel gterm
// (K 128->64) and skips masked rows (t >= num_pts). All inputs f32.
// ---------------------------------------------------------------------------
__global__ __launch_bounds__(64, 2) void vfe_kernel(
    const float* __restrict__ vox, const int* __restrict__ npts,
    const float* __restrict__ w1, const float* __restrict__ g1, const float* __restrict__ b1,
    const float* __restrict__ rm1, const float* __restrict__ rv1,
    const float* __restrict__ w2, const float* __restrict__ g2, const float* __restrict__ b2,
    const float* __restrict__ rm2, const float* __restrict__ rv2,
    float* __restrict__ vf, int N)
{
  __shared__ __align__(16) float featL[32 * 12];
  __shared__ __align__(16) float h1L[32 * 68];   // stride 68: float4-aligned rows
  __shared__ __align__(16) float gmaxL[64];

  const int c = threadIdx.x;

  float w1c[9];
#pragma unroll
  for (int k = 0; k < 9; ++k) w1c[k] = w1[k * 64 + c];
  float sc1 = g1[c] * rsqrtf(rv1[c] + EPSV);
  float sh1 = b1[c] - rm1[c] * sc1;
  float sc2 = g2[c] * rsqrtf(rv2[c] + EPSV);
  float sh2 = b2[c] - rm2[c] * sc2;
  float w2c[128];
#pragma unroll
  for (int j = 0; j < 128; ++j) w2c[j] = w2[j * 64 + c];

  for (int v = blockIdx.x; v < N; v += gridDim.x) {
    int n = npts[v];
    float x = 0.f, y = 0.f, z = 0.f, w = 0.f;
    if (c < 32) {
      float4 u = *(const float4*)(vox + ((size_t)v * 32 + c) * 4);
      x = u.x; y = u.y; z = u.z; w = u.w;
    }
    // unmasked sums over all 32 points (reference divides unmasked sum by n)
    float sx = x, sy = y, sz = z;
#pragma unroll
    for (int off = 32; off >= 1; off >>= 1) {
      sx += __shfl_xor(sx, off);
      sy += __shfl_xor(sy, off);
      sz += __shfl_xor(sz, off);
    }
    float nf = (float)n;
    float mx = sx / nf, my = sy / nf, mz = sz / nf;
    if (c < 32) {
      float* f = &featL[c * 12];
      f[0] = x; f[1] = y; f[2] = z; f[3] = w;
      f[4] = x - mx; f[5] = y - my; f[6] = z - mz;
      f[7] = x - mx; f[8] = y - my;
    }
    __syncthreads();

    // layer 1: all 32 rows (gmax1 is over unmasked rows)
    float gmax = 0.f;
#pragma unroll
    for (int t = 0; t < 32; ++t) {
      float acc = 0.f;
#pragma unroll
      for (int k = 0; k < 9; ++k) acc += featL[t * 12 + k] * w1c[k];
      float h = fmaxf(acc * sc1 + sh1, 0.f);
      h1L[t * 68 + c] = h;
      gmax = fmaxf(gmax, h);
    }
    gmaxL[c] = gmax;
    __syncthreads();

    float gterm = 0.f;
#pragma unroll
    for (int j = 0; j < 64; j += 4) {
      float4 g4 = *(const float4*)&gmaxL[j];
      gterm += g4.x * w2c[64 + j] + g4.y * w2c[64 + j + 1] +
               g4.z * w2c[64 + j + 2] + g4.w * w2c[64 + j + 3];
    }

    // layer 2 only for valid rows; final = max over valid rows (relu >= 0)
    float vmax = 0.f;
    for (int t = 0; t < n; ++t) {
      float acc = gterm;
#pragma unroll
      for (int j = 0; j < 64; j += 4) {
        float4 h4 = *(const float4*)&h1L[t * 68 + j];
        acc += h4.x * w2c[j] + h4.y * w2c[j + 1] + h4.z * w2c[j + 2] + h4.w * w2c[j + 3];
      }
      float h2 = fmaxf(acc * sc2 + sh2, 0.f);
      vmax = fmaxf(vmax, h2);
    }
    vf[(size_t)v * 64 + c] = vmax;
    __syncthreads();   // protect featL/h1L before next voxel
  }
}

// ---------------------------------------------------------------------------
// Scatter pass 1: last-write-wins == max voxel index per cell
// ---------------------------------------------------------------------------
__global__ void winner_kernel(const int* __restrict__ coords, int* __restrict__ win,
                              int N, int H, int W) {
  int v = blockIdx.x * blockDim.x + threadIdx.x;
  if (v >= N) return;
  int b = coords[v * 4 + 0];
  int y = min(max(coords[v * 4 + 2], 0), H - 1);
  int x = min(max(coords[v * 4 + 3], 0), W - 1);
  atomicMax(&win[(b * H + y) * W + x], v);
}

// ---------------------------------------------------------------------------
// Scatter pass 2 + zero-fill: writes every cell (winner's vf or 0) -> no memset
// dst NHWC bf16 with channel stride cstride (128 for cat buffers, 64 for g2)
// ---------------------------------------------------------------------------
__global__ void fill_kernel(const int* __restrict__ win, const float* __restrict__ vf,
                            u16* __restrict__ dst, int cells, int cstride) {
  int i = blockIdx.x * blockDim.x + threadIdx.x;
  if (i >= cells * 64) return;
  int cell = i >> 6, c = i & 63;
  int wv = win[cell];
  float val = (wv >= 0) ? vf[(size_t)wv * 64 + c] : 0.f;
  dst[(size_t)cell * cstride + c] = f2bf(val);
}

// ---------------------------------------------------------------------------
// Bilinear 2x upsample (jax.image.resize semantics: half-pixel, edge-folded
// weights 0.25/0.75). src NHWC stride 64 bf16, dst NHWC stride `dstride`.
// ---------------------------------------------------------------------------
__global__ void upsample_kernel(const u16* __restrict__ src, u16* __restrict__ dst,
                                int Hc, int Wc, int dstride, int doff, int total) {
  int i = blockIdx.x * blockDim.x + threadIdx.x;
  if (i >= total) return;
  int c = i & 63;
  int px = i >> 6;
  int W2 = Wc * 2, H2 = Hc * 2;
  int x = px % W2; int t = px / W2; int y = t % H2; int n = t / H2;
  int ky = y >> 1, kx = x >> 1;
  int ya, yb, xa, xb; float wya, wxa;
  if ((y & 1) == 0) { ya = ky > 0 ? ky - 1 : 0; yb = ky; wya = 0.25f; }
  else              { ya = ky; yb = (ky + 1 < Hc) ? ky + 1 : Hc - 1; wya = 0.75f; }
  if ((x & 1) == 0) { xa = kx > 0 ? kx - 1 : 0; xb = kx; wxa = 0.25f; }
  else              { xa = kx; xb = (kx + 1 < Wc) ? kx + 1 : Wc - 1; wxa = 0.75f; }
  float wyb = 1.f - wya, wxb = 1.f - wxa;
  const u16* sp = src + c;
  float vaa = bf2f(sp[((size_t)(n * Hc + ya) * Wc + xa) * 64]);
  float vab = bf2f(sp[((size_t)(n * Hc + ya) * Wc + xb) * 64]);
  float vba = bf2f(sp[((size_t)(n * Hc + yb) * Wc + xa) * 64]);
  float vbb = bf2f(sp[((size_t)(n * Hc + yb) * Wc + xb) * 64]);
  float v = wya * (wxa * vaa + wxb * vab) + wyb * (wxa * vba + wxb * vbb);
  dst[(size_t)px * dstride + doff + c] = f2bf(v);
}

// ---------------------------------------------------------------------------
// Conv3x3 + BN + ReLU, implicit GEMM with bf16 MFMA 16x16x32.
// Block: 256 thr (4 waves). Output tile: 4 rows x 32 x-px x 64 co (wave = 1
// row, M=32 px, N=64 co -> 2x4 frags). Input NHWC(128) bf16 staged to LDS in
// ci-halves with halo; weights fwT [kyx][co][ci] staged per tap as B ([n][k]
// rows, gemm_bt pattern). NCHW_OUT: LDS-transpose epilogue, f32 d_out.
// ---------------------------------------------------------------------------
template<int H, int W, bool NCHW_OUT>
__global__ __launch_bounds__(256, 2) void conv_kernel(
    const u16* __restrict__ in, const u16* __restrict__ wT,
    const float* __restrict__ fg, const float* __restrict__ fb,
    const float* __restrict__ fm, const float* __restrict__ fv,
    void* __restrict__ outv)
{
  constexpr int XT = 32, YT = 4;
  constexpr int XTILES = (W + XT - 1) / XT;
  constexpr int CIP = 72;                      // 64-ci half + 8 pad
  __shared__ __align__(16) union {
    struct { u16 A[204 * CIP]; u16 B[64 * CIP]; } s;
    float T[4 * 64 * 33];                      // epilogue transpose (NCHW path)
  } lds;

  const int tid = threadIdx.x;
  const int lane = tid & 63;
  const int wv = tid >> 6;                     // wave id == output row in tile
  const int m16 = lane & 15;
  const int q = lane >> 4;

  int bid = blockIdx.x;
  const int xt = bid % XTILES; bid /= XTILES;
  const int yt = bid % (H / YT);
  const int n = bid / (H / YT);
  const int x0 = xt * XT, y0 = yt * YT;

  float sc[4], sh[4];
#pragma unroll
  for (int nf = 0; nf < 4; ++nf) {
    int co = nf * 16 + m16;
    float s = fg[co] * rsqrtf(fv[co] + EPSV);
    sc[nf] = s;
    sh[nf] = fb[co] - fm[co] * s;
  }

  f32x4 acc[2][4];
#pragma unroll
  for (int mf = 0; mf < 2; ++mf)
#pragma unroll
    for (int nf = 0; nf < 4; ++nf)
      acc[mf][nf] = (f32x4){0.f, 0.f, 0.f, 0.f};

  for (int hf = 0; hf < 2; ++hf) {
    __syncthreads();                           // prior reads of lds.s.A done
    {   // stage A half: 204 halo pixels x 64 ci, zero-filled OOB
      const int cis = (tid & 7) * 8;
      for (int it = 0; it < 7; ++it) {
        int p = (tid >> 3) + it * 32;
        if (p < 204) {
          int r = p / 34, xx = p - r * 34;
          int gy = y0 - 1 + r, gx = x0 - 1 + xx;
          uint4 v = make_uint4(0, 0, 0, 0);
          if (gy >= 0 && gy < H && gx >= 0 && gx < W)
            v = *(const uint4*)(in + ((size_t)((n * H + gy) * W + gx) * 128 + hf * 64 + cis));
          *(uint4*)&lds.s.A[p * CIP + cis] = v;
        }
      }
    }
    for (int kyx = 0; kyx < 9; ++kyx) {
      __syncthreads();                         // prior reads of lds.s.B done (+A staged)
      {   // stage B: 64co x 64ci(half) for this tap
#pragma unroll
        for (int it = 0; it < 2; ++it) {
          int e8 = (it * 256 + tid) * 8;
          int co = e8 >> 6, ci = e8 & 63;
          uint4 v = *(const uint4*)(wT + (kyx * 8192 + co * 128 + hf * 64 + ci));
          *(uint4*)&lds.s.B[co * CIP + ci] = v;
        }
      }
      __syncthreads();
      const int ky = kyx / 3, kx = kyx - ky * 3;
#pragma unroll
      for (int cc = 0; cc < 2; ++cc) {
        bf16x8 a[2], b[4];
#pragma unroll
        for (int mf = 0; mf < 2; ++mf) {
          int p = (wv + ky) * 34 + (mf * 16 + m16) + kx;
          a[mf] = *(const bf16x8*)&lds.s.A[p * CIP + cc * 32 + q * 8];
        }
#pragma unroll
        for (int nf = 0; nf < 4; ++nf)
          b[nf] = *(const bf16x8*)&lds.s.B[(nf * 16 + m16) * CIP + cc * 32 + q * 8];
#pragma unroll
        for (int mf = 0; mf < 2; ++mf)
#pragma unroll
          for (int nf = 0; nf < 4; ++nf)
            acc[mf][nf] = __builtin_amdgcn_mfma_f32_16x16x32_bf16(a[mf], b[nf], acc[mf][nf], 0, 0, 0);
      }
    }
  }

  const int y = y0 + wv;
  if (!NCHW_OUT) {
    // NHWC(64) bf16 direct store (internal fused1 buffer)
    u16* out = (u16*)outv;
#pragma unroll
    for (int mf = 0; mf < 2; ++mf)
#pragma unroll
      for (int nf = 0; nf < 4; ++nf)
#pragma unroll
        for (int r = 0; r < 4; ++r) {
          int px = mf * 16 + q * 4 + r;
          int x = x0 + px;
          if (x < W) {
            int co = nf * 16 + m16;
            float v = fmaxf(acc[mf][nf][r] * sc[nf] + sh[nf], 0.f);
            out[((size_t)(n * H + y) * W + x) * 64 + co] = f2bf(v);
          }
        }
  } else {
    // NCHW f32 d_out: transpose via LDS for x-contiguous stores
    float* out = (float*)outv;
    __syncthreads();                           // K-loop reads of lds.s done
    float* T = &lds.T[wv * 64 * 33];
#pragma unroll
    for (int mf = 0; mf < 2; ++mf)
#pragma unroll
      for (int nf = 0; nf < 4; ++nf)
#pragma unroll
        for (int r = 0; r < 4; ++r) {
          int px = mf * 16 + q * 4 + r;
          int co = nf * 16 + m16;
          T[co * 33 + px] = fmaxf(acc[mf][nf][r] * sc[nf] + sh[nf], 0.f);
        }
    __syncthreads();
    const int px = lane & 31, co2 = lane >> 5;
    int x = x0 + px;
#pragma unroll 4
    for (int it = 0; it < 32; ++it) {
      int co = it * 2 + co2;
      float v = T[co * 33 + px];
      if (x < W) out[((size_t)(n * 64 + co) * H + y) * W + x] = v;
    }
  }
}

// ---------------------------------------------------------------------------
extern "C" void kernel_launch(void* const* d_in, const int* in_sizes, int n_in,
                              void* d_out, int out_size, void* d_ws, size_t ws_size,
                              hipStream_t stream) {
  // Input-order detection: dict order has num_pts_0 (40000) at [1];
  // reference-signature order has voxels_1 (2,560,000) at [1].
  int I_vox[3], I_np[3], I_co[3];
  int I_w1, I_g1, I_b1, I_rm1, I_rv1, I_w2, I_g2, I_b2, I_rm2, I_rv2;
  int I_fw, I_fg, I_fb, I_fm, I_fv;
  if (in_sizes[1] == 40000) {
    I_vox[0] = 0; I_np[0] = 1; I_co[0] = 2;
    I_vox[1] = 3; I_np[1] = 4; I_co[1] = 5;
    I_vox[2] = 6; I_np[2] = 7; I_co[2] = 8;
    I_w1 = 9; I_g1 = 10; I_b1 = 11; I_rm1 = 12; I_rv1 = 13;
    I_w2 = 14; I_g2 = 15; I_b2 = 16; I_rm2 = 17; I_rv2 = 18;
    I_fw = 19; I_fg = 20; I_fb = 21; I_fm = 22; I_fv = 23;
  } else {
    I_vox[0] = 0; I_vox[1] = 1; I_vox[2] = 2;
    I_w1 = 3; I_g1 = 4; I_b1 = 5; I_rm1 = 6; I_rv1 = 7;
    I_w2 = 8; I_g2 = 9; I_b2 = 10; I_rm2 = 11; I_rv2 = 12;
    I_fw = 13; I_fg = 14; I_fb = 15; I_fm = 16; I_fv = 17;
    I_np[0] = 18; I_np[1] = 19; I_np[2] = 20;
    I_co[0] = 21; I_co[1] = 22; I_co[2] = 23;
  }

  const int HS[3] = {496, 248, 124};
  const int WS[3] = {432, 216, 108};
  int Nv[3];
  for (int s = 0; s < 3; ++s) Nv[s] = in_sizes[I_np[s]];

  // workspace carve-up
  char* wsp = (char*)d_ws;
  size_t off = 0;
  auto take = [&](size_t bytes) -> void* {
    void* p = wsp + off;
    off = (off + bytes + 255) & ~(size_t)255;
    return p;
  };
  float* vf[3]; int* win[3];
  for (int s = 0; s < 3; ++s) vf[s] = (float*)take((size_t)Nv[s] * 64 * 4);
  int cells[3];
  for (int s = 0; s < 3; ++s) {
    cells[s] = 4 * HS[s] * WS[s];
    win[s] = (int*)take((size_t)cells[s] * 4);
  }
  u16* buf0 = (u16*)take((size_t)cells[0] * 128 * 2);   // (4,496,432,128) NHWC bf16
  u16* buf1 = (u16*)take((size_t)cells[1] * 128 * 2);   // (4,248,216,128)
  u16* g2b  = (u16*)take((size_t)cells[2] * 64 * 2);    // (4,124,108,64)
  u16* fus1 = (u16*)take((size_t)cells[1] * 64 * 2);    // (4,248,216,64)
  u16* fwT  = (u16*)take((size_t)2 * 9 * 64 * 128 * 2);

  const float* W1 = (const float*)d_in[I_w1];
  const float* G1 = (const float*)d_in[I_g1];
  const float* B1 = (const float*)d_in[I_b1];
  const float* RM1 = (const float*)d_in[I_rm1];
  const float* RV1 = (const float*)d_in[I_rv1];
  const float* W2 = (const float*)d_in[I_w2];
  const float* G2 = (const float*)d_in[I_g2];
  const float* B2 = (const float*)d_in[I_b2];
  const float* RM2 = (const float*)d_in[I_rm2];
  const float* RV2 = (const float*)d_in[I_rv2];
  const float* FW = (const float*)d_in[I_fw];
  const float* FG = (const float*)d_in[I_fg];
  const float* FB = (const float*)d_in[I_fb];
  const float* FM = (const float*)d_in[I_fm];
  const float* FV = (const float*)d_in[I_fv];

  for (int s = 0; s < 3; ++s)
    hipMemsetAsync(win[s], 0xFF, (size_t)cells[s] * 4, stream);

  twt_kernel<<<(2 * 9 * 64 * 128 + 255) / 256, 256, 0, stream>>>(FW, fwT);

  for (int s = 0; s < 3; ++s) {
    vfe_kernel<<<2048, 64, 0, stream>>>(
        (const float*)d_in[I_vox[s]], (const int*)d_in[I_np[s]],
        W1 + s * 9 * 64, G1 + s * 64, B1 + s * 64, RM1 + s * 64, RV1 + s * 64,
        W2 + s * 128 * 64, G2 + s * 64, B2 + s * 64, RM2 + s * 64, RV2 + s * 64,
        vf[s], Nv[s]);
  }
  for (int s = 0; s < 3; ++s) {
    winner_kernel<<<(Nv[s] + 255) / 256, 256, 0, stream>>>(
        (const int*)d_in[I_co[s]], win[s], Nv[s], HS[s], WS[s]);
  }
  fill_kernel<<<(cells[0] * 64 + 255) / 256, 256, 0, stream>>>(win[0], vf[0], buf0, cells[0], 128);
  fill_kernel<<<(cells[1] * 64 + 255) / 256, 256, 0, stream>>>(win[1], vf[1], buf1, cells[1], 128);
  fill_kernel<<<(cells[2] * 64 + 255) / 256, 256, 0, stream>>>(win[2], vf[2], g2b, cells[2], 64);

  {   // upsample g2 (124,108) -> buf1 ch64..127 (248,216)
    int total = cells[1] * 64;
    upsample_kernel<<<(total + 255) / 256, 256, 0, stream>>>(g2b, buf1, 124, 108, 128, 64, total);
  }
  conv_kernel<248, 216, false><<<4 * (248 / 4) * 7, 256, 0, stream>>>(
      buf1, fwT + 9 * 64 * 128, FG + 64, FB + 64, FM + 64, FV + 64, fus1);
  {   // upsample fused1 (248,216) -> buf0 ch64..127 (496,432)
    int total = cells[0] * 64;
    upsample_kernel<<<(total + 255) / 256, 256, 0, stream>>>(fus1, buf0, 248, 216, 128, 64, total);
  }
  conv_kernel<496, 432, true><<<4 * (496 / 4) * 14, 256, 0, stream>>>(
      buf0, fwT, FG, FB, FM, FV, (float*)d_out);
}

// Round 3
// 952.324 us; speedup vs baseline: 1.4314x; 1.4314x over previous
//
#include <hip/hip_runtime.h>

typedef unsigned short u16;
typedef short bf16x8 __attribute__((ext_vector_type(8)));
typedef float f32x4 __attribute__((ext_vector_type(4)));

#define EPSV 1e-3f

__device__ __forceinline__ float bf2f(u16 u) {
  union { unsigned int i; float f; } x; x.i = ((unsigned int)u) << 16; return x.f;
}
__device__ __forceinline__ u16 f2bf(float f) {
  union { float f; unsigned int i; } x; x.f = f;
  unsigned int r = x.i + 0x7fffu + ((x.i >> 16) & 1u);   // RNE
  return (u16)(r >> 16);
}

// wave-internal LDS handoff fence: drain DS pipe + stop compiler reordering
#define WAVE_FENCE() do { __builtin_amdgcn_s_waitcnt(0); __builtin_amdgcn_wave_barrier(); } while (0)

// ---------------------------------------------------------------------------
// Weight transform: fw (2,64,128,3,3) f32 -> fwT [set][ky*3+kx][co][ci] bf16
// ---------------------------------------------------------------------------
__global__ void twt_kernel(const float* __restrict__ fw, u16* __restrict__ fwT) {
  int i = blockIdx.x * blockDim.x + threadIdx.x;
  if (i >= 2 * 9 * 64 * 128) return;
  int ci = i & 127;
  int r = i >> 7;
  int co = r & 63; r >>= 6;
  int kyx = r % 9;
  int set = r / 9;
  fwT[i] = f2bf(fw[(((set * 64 + co) * 128 + ci) * 9) + kyx]);
}

// ---------------------------------------------------------------------------
// VFE via MFMA. One wave per voxel (4 waves/block, private LDS regions).
// Layer1: D1[t][c] = feat(32xK32,padded) x W1T  (8 MFMA)
// gterm:  row-0-only MFMA: A row0 = gmax1 -> D[0][c] = sum_j gmax1[j]*w2hi[j][c]
// Layer2: D2[t][c] = h1(32xK64) x W2loT + gterm (16 MFMA), mask t<n, max.
// Weight B-fragments persist in VGPRs (built once from LDS-staged transposed
// weights); per-voxel LDS traffic is A-frags + h1 round-trip only.
// Fragment mapping (HW-verified via round-2 conv): A/B rows: row=lane&15,
// k=(lane>>4)*8+i ; D: col(c)=lane&15, row(t)=(lane>>4)*4+reg.
// ---------------------------------------------------------------------------
__global__ __launch_bounds__(256, 2) void vfe_mfma_kernel(
    const float* __restrict__ vox, const int* __restrict__ npts,
    const float* __restrict__ w1, const float* __restrict__ g1, const float* __restrict__ b1,
    const float* __restrict__ rm1, const float* __restrict__ rv1,
    const float* __restrict__ w2, const float* __restrict__ g2, const float* __restrict__ b2,
    const float* __restrict__ rm2, const float* __restrict__ rv2,
    float* __restrict__ vf, int N)
{
  struct PerWave {
    u16 X[32 * 72];   // h1 bf16 [t][j], stride 72 (64+8 pad)
    u16 F[32 * 40];   // feat bf16 [t][k], stride 40 (32+8 pad)
    u16 G[64];        // gmax1 bf16
  };
  __shared__ __align__(16) union {
    struct { u16 W1T[64 * 40]; u16 W2T[64 * 136]; } w;   // transposed weights (transient)
    PerWave r[4];
  } lds;

  const int tid = threadIdx.x;
  const int lane = tid & 63;
  const int wv = tid >> 6;
  const int m16 = lane & 15;
  const int q = lane >> 4;

  // ---- stage transposed bf16 weights to LDS (once per block) ----
  for (int i = tid; i < 64 * 40; i += 256) {
    int c = i / 40, k = i % 40;
    lds.w.W1T[i] = f2bf(k < 9 ? w1[k * 64 + c] : 0.f);
  }
  for (int i = tid; i < 64 * 136; i += 256) {
    int c = i / 136, j = i % 136;
    lds.w.W2T[i] = f2bf(j < 128 ? w2[j * 64 + c] : 0.f);
  }
  __syncthreads();

  // ---- build persistent B-fragments in VGPRs ----
  bf16x8 bW1[4], bLo[4][2], bHi[4][2];
  float sc1[4], sh1[4], sc2[4], sh2[4];
#pragma unroll
  for (int nf = 0; nf < 4; ++nf) {
    int c = nf * 16 + m16;
    bW1[nf] = *(const bf16x8*)&lds.w.W1T[c * 40 + q * 8];
#pragma unroll
    for (int ks = 0; ks < 2; ++ks) {
      bLo[nf][ks] = *(const bf16x8*)&lds.w.W2T[c * 136 + ks * 32 + q * 8];
      bHi[nf][ks] = *(const bf16x8*)&lds.w.W2T[c * 136 + 64 + ks * 32 + q * 8];
    }
    float s1 = g1[c] * rsqrtf(rv1[c] + EPSV);
    sc1[nf] = s1; sh1[nf] = b1[c] - rm1[c] * s1;
    float s2 = g2[c] * rsqrtf(rv2[c] + EPSV);
    sc2[nf] = s2; sh2[nf] = b2[c] - rm2[c] * s2;
  }
  __syncthreads();   // weight region now reusable as per-wave scratch

  u16* X = lds.r[wv].X;
  u16* F = lds.r[wv].F;
  u16* G = lds.r[wv].G;
  // zero F once (covers k=16..31 pad region; k<16 rewritten per voxel)
  for (int i = lane; i < 640; i += 64) ((unsigned int*)F)[i] = 0u;

  const int wgid = blockIdx.x * 4 + wv;
  const int wstride = gridDim.x * 4;

  for (int v = wgid; v < N; v += wstride) {
    const int n = npts[v];
    // ---- load points, means, feat staging ----
    float px = 0.f, py = 0.f, pz = 0.f, pw = 0.f;
    if (lane < 32) {
      float4 u = *(const float4*)(vox + ((size_t)v * 32 + lane) * 4);
      px = u.x; py = u.y; pz = u.z; pw = u.w;
    }
    float sx = px, sy = py, sz = pz;
#pragma unroll
    for (int off = 32; off >= 1; off >>= 1) {
      sx += __shfl_xor(sx, off);
      sy += __shfl_xor(sy, off);
      sz += __shfl_xor(sz, off);
    }
    float nf_ = (float)n;
    float mx = sx / nf_, my = sy / nf_, mz = sz / nf_;
    if (lane < 32) {
      float dx = px - mx, dy = py - my, dz = pz - mz;
      bf16x8 r0, r1;
      r0[0] = (short)f2bf(px); r0[1] = (short)f2bf(py);
      r0[2] = (short)f2bf(pz); r0[3] = (short)f2bf(pw);
      r0[4] = (short)f2bf(dx); r0[5] = (short)f2bf(dy);
      r0[6] = (short)f2bf(dz); r0[7] = (short)f2bf(dx);
      r1 = (bf16x8){0, 0, 0, 0, 0, 0, 0, 0};
      r1[0] = (short)f2bf(dy);
      *(bf16x8*)&F[lane * 40 + 0] = r0;
      *(bf16x8*)&F[lane * 40 + 8] = r1;
    }
    WAVE_FENCE();

    // ---- layer 1: 32x64 x K32 ----
    bf16x8 a1[2];
    a1[0] = *(const bf16x8*)&F[m16 * 40 + q * 8];
    a1[1] = *(const bf16x8*)&F[(16 + m16) * 40 + q * 8];
    f32x4 acc1[2][4];
#pragma unroll
    for (int mf = 0; mf < 2; ++mf)
#pragma unroll
      for (int nf = 0; nf < 4; ++nf) {
        acc1[mf][nf] = (f32x4){0.f, 0.f, 0.f, 0.f};
        acc1[mf][nf] = __builtin_amdgcn_mfma_f32_16x16x32_bf16(a1[mf], bW1[nf], acc1[mf][nf], 0, 0, 0);
      }

    // bn1+relu -> h1 to X (bf16), per-channel gmax
    float gmx[4] = {0.f, 0.f, 0.f, 0.f};
#pragma unroll
    for (int mf = 0; mf < 2; ++mf)
#pragma unroll
      for (int nf = 0; nf < 4; ++nf)
#pragma unroll
        for (int r = 0; r < 4; ++r) {
          float h = fmaxf(acc1[mf][nf][r] * sc1[nf] + sh1[nf], 0.f);
          gmx[nf] = fmaxf(gmx[nf], h);
          int t = mf * 16 + q * 4 + r;
          X[t * 72 + nf * 16 + m16] = f2bf(h);
        }
#pragma unroll
    for (int nf = 0; nf < 4; ++nf) {
      gmx[nf] = fmaxf(gmx[nf], __shfl_xor(gmx[nf], 16));
      gmx[nf] = fmaxf(gmx[nf], __shfl_xor(gmx[nf], 32));
    }
    if (q == 0) {
#pragma unroll
      for (int nf = 0; nf < 4; ++nf) G[nf * 16 + m16] = f2bf(gmx[nf]);
    }
    WAVE_FENCE();

    // ---- gterm[c] = sum_j gmax1[j] * w2[64+j][c] via row-0 MFMA ----
    f32x4 ga[4];
#pragma unroll
    for (int nf = 0; nf < 4; ++nf) ga[nf] = (f32x4){0.f, 0.f, 0.f, 0.f};
#pragma unroll
    for (int ks = 0; ks < 2; ++ks) {
      bf16x8 ag = (bf16x8){0, 0, 0, 0, 0, 0, 0, 0};
      if (m16 == 0) ag = *(const bf16x8*)&G[ks * 32 + q * 8];
#pragma unroll
      for (int nf = 0; nf < 4; ++nf)
        ga[nf] = __builtin_amdgcn_mfma_f32_16x16x32_bf16(ag, bHi[nf][ks], ga[nf], 0, 0, 0);
    }
    float gt[4];
#pragma unroll
    for (int nf = 0; nf < 4; ++nf) {
      float s = ga[nf][0] + ga[nf][1] + ga[nf][2] + ga[nf][3];  // rows != 0 are zero
      s += __shfl_xor(s, 16);
      s += __shfl_xor(s, 32);
      gt[nf] = s;
    }

    // ---- layer 2: 32x64 x K64, acc init = gterm ----
    f32x4 acc2[2][4];
#pragma unroll
    for (int mf = 0; mf < 2; ++mf)
#pragma unroll
      for (int nf = 0; nf < 4; ++nf)
        acc2[mf][nf] = (f32x4){gt[nf], gt[nf], gt[nf], gt[nf]};
#pragma unroll
    for (int ks = 0; ks < 2; ++ks) {
      bf16x8 a2[2];
      a2[0] = *(const bf16x8*)&X[m16 * 72 + ks * 32 + q * 8];
      a2[1] = *(const bf16x8*)&X[(16 + m16) * 72 + ks * 32 + q * 8];
#pragma unroll
      for (int mf = 0; mf < 2; ++mf)
#pragma unroll
        for (int nf = 0; nf < 4; ++nf)
          acc2[mf][nf] = __builtin_amdgcn_mfma_f32_16x16x32_bf16(a2[mf], bLo[nf][ks], acc2[mf][nf], 0, 0, 0);
    }

    // ---- bn2+relu, mask t<n, max over t ----
    float vm[4] = {0.f, 0.f, 0.f, 0.f};
#pragma unroll
    for (int mf = 0; mf < 2; ++mf)
#pragma unroll
      for (int nf = 0; nf < 4; ++nf)
#pragma unroll
        for (int r = 0; r < 4; ++r) {
          int t = mf * 16 + q * 4 + r;
          float h2 = fmaxf(acc2[mf][nf][r] * sc2[nf] + sh2[nf], 0.f);
          if (t < n) vm[nf] = fmaxf(vm[nf], h2);
        }
#pragma unroll
    for (int nf = 0; nf < 4; ++nf) {
      vm[nf] = fmaxf(vm[nf], __shfl_xor(vm[nf], 16));
      vm[nf] = fmaxf(vm[nf], __shfl_xor(vm[nf], 32));
    }
    float outv = (q == 0) ? vm[0] : (q == 1) ? vm[1] : (q == 2) ? vm[2] : vm[3];
    vf[(size_t)v * 64 + q * 16 + m16] = outv;
    __builtin_amdgcn_wave_barrier();   // keep next-iter F writes after this-iter X reads
  }
}

// ---------------------------------------------------------------------------
// Scatter pass 1: last-write-wins == max voxel index per cell
// ---------------------------------------------------------------------------
__global__ void winner_kernel(const int* __restrict__ coords, int* __restrict__ win,
                              int N, int H, int W) {
  int v = blockIdx.x * blockDim.x + threadIdx.x;
  if (v >= N) return;
  int b = coords[v * 4 + 0];
  int y = min(max(coords[v * 4 + 2], 0), H - 1);
  int x = min(max(coords[v * 4 + 3], 0), W - 1);
  atomicMax(&win[(b * H + y) * W + x], v);
}

// ---------------------------------------------------------------------------
// Scatter pass 2 + zero-fill: writes every cell (winner's vf or 0) -> no memset
// dst NHWC bf16 with channel stride cstride (128 for cat buffers, 64 for g2)
// ---------------------------------------------------------------------------
__global__ void fill_kernel(const int* __restrict__ win, const float* __restrict__ vf,
                            u16* __restrict__ dst, int cells, int cstride) {
  int i = blockIdx.x * blockDim.x + threadIdx.x;
  if (i >= cells * 64) return;
  int cell = i >> 6, c = i & 63;
  int wv = win[cell];
  float val = (wv >= 0) ? vf[(size_t)wv * 64 + c] : 0.f;
  dst[(size_t)cell * cstride + c] = f2bf(val);
}

// ---------------------------------------------------------------------------
// Bilinear 2x upsample (jax.image.resize semantics: half-pixel, edge-folded
// weights 0.25/0.75). src NHWC stride 64 bf16, dst NHWC stride `dstride`.
// ---------------------------------------------------------------------------
__global__ void upsample_kernel(const u16* __restrict__ src, u16* __restrict__ dst,
                                int Hc, int Wc, int dstride, int doff, int total) {
  int i = blockIdx.x * blockDim.x + threadIdx.x;
  if (i >= total) return;
  int c = i & 63;
  int px = i >> 6;
  int W2 = Wc * 2, H2 = Hc * 2;
  int x = px % W2; int t = px / W2; int y = t % H2; int n = t / H2;
  int ky = y >> 1, kx = x >> 1;
  int ya, yb, xa, xb; float wya, wxa;
  if ((y & 1) == 0) { ya = ky > 0 ? ky - 1 : 0; yb = ky; wya = 0.25f; }
  else              { ya = ky; yb = (ky + 1 < Hc) ? ky + 1 : Hc - 1; wya = 0.75f; }
  if ((x & 1) == 0) { xa = kx > 0 ? kx - 1 : 0; xb = kx; wxa = 0.25f; }
  else              { xa = kx; xb = (kx + 1 < Wc) ? kx + 1 : Wc - 1; wxa = 0.75f; }
  float wyb = 1.f - wya, wxb = 1.f - wxa;
  const u16* sp = src + c;
  float vaa = bf2f(sp[((size_t)(n * Hc + ya) * Wc + xa) * 64]);
  float vab = bf2f(sp[((size_t)(n * Hc + ya) * Wc + xb) * 64]);
  float vba = bf2f(sp[((size_t)(n * Hc + yb) * Wc + xa) * 64]);
  float vbb = bf2f(sp[((size_t)(n * Hc + yb) * Wc + xb) * 64]);
  float v = wya * (wxa * vaa + wxb * vab) + wyb * (wxa * vba + wxb * vbb);
  dst[(size_t)px * dstride + doff + c] = f2bf(v);
}

// ---------------------------------------------------------------------------
// Conv3x3 + BN + ReLU, implicit GEMM with bf16 MFMA 16x16x32. (unchanged)
// ---------------------------------------------------------------------------
template<int H, int W, bool NCHW_OUT>
__global__ __launch_bounds__(256, 2) void conv_kernel(
    const u16* __restrict__ in, const u16* __restrict__ wT,
    const float* __restrict__ fg, const float* __restrict__ fb,
    const float* __restrict__ fm, const float* __restrict__ fv,
    void* __restrict__ outv)
{
  constexpr int XT = 32, YT = 4;
  constexpr int XTILES = (W + XT - 1) / XT;
  constexpr int CIP = 72;                      // 64-ci half + 8 pad
  __shared__ __align__(16) union {
    struct { u16 A[204 * CIP]; u16 B[64 * CIP]; } s;
    float T[4 * 64 * 33];                      // epilogue transpose (NCHW path)
  } lds;

  const int tid = threadIdx.x;
  const int lane = tid & 63;
  const int wv = tid >> 6;                     // wave id == output row in tile
  const int m16 = lane & 15;
  const int q = lane >> 4;

  int bid = blockIdx.x;
  const int xt = bid % XTILES; bid /= XTILES;
  const int yt = bid % (H / YT);
  const int n = bid / (H / YT);
  const int x0 = xt * XT, y0 = yt * YT;

  float sc[4], sh[4];
#pragma unroll
  for (int nf = 0; nf < 4; ++nf) {
    int co = nf * 16 + m16;
    float s = fg[co] * rsqrtf(fv[co] + EPSV);
    sc[nf] = s;
    sh[nf] = fb[co] - fm[co] * s;
  }

  f32x4 acc[2][4];
#pragma unroll
  for (int mf = 0; mf < 2; ++mf)
#pragma unroll
    for (int nf = 0; nf < 4; ++nf)
      acc[mf][nf] = (f32x4){0.f, 0.f, 0.f, 0.f};

  for (int hf = 0; hf < 2; ++hf) {
    __syncthreads();                           // prior reads of lds.s.A done
    {   // stage A half: 204 halo pixels x 64 ci, zero-filled OOB
      const int cis = (tid & 7) * 8;
      for (int it = 0; it < 7; ++it) {
        int p = (tid >> 3) + it * 32;
        if (p < 204) {
          int r = p / 34, xx = p - r * 34;
          int gy = y0 - 1 + r, gx = x0 - 1 + xx;
          uint4 v = make_uint4(0, 0, 0, 0);
          if (gy >= 0 && gy < H && gx >= 0 && gx < W)
            v = *(const uint4*)(in + ((size_t)((n * H + gy) * W + gx) * 128 + hf * 64 + cis));
          *(uint4*)&lds.s.A[p * CIP + cis] = v;
        }
      }
    }
    for (int kyx = 0; kyx < 9; ++kyx) {
      __syncthreads();                         // prior reads of lds.s.B done (+A staged)
      {   // stage B: 64co x 64ci(half) for this tap
#pragma unroll
        for (int it = 0; it < 2; ++it) {
          int e8 = (it * 256 + tid) * 8;
          int co = e8 >> 6, ci = e8 & 63;
          uint4 v = *(const uint4*)(wT + (kyx * 8192 + co * 128 + hf * 64 + ci));
          *(uint4*)&lds.s.B[co * CIP + ci] = v;
        }
      }
      __syncthreads();
      const int ky = kyx / 3, kx = kyx - ky * 3;
#pragma unroll
      for (int cc = 0; cc < 2; ++cc) {
        bf16x8 a[2], b[4];
#pragma unroll
        for (int mf = 0; mf < 2; ++mf) {
          int p = (wv + ky) * 34 + (mf * 16 + m16) + kx;
          a[mf] = *(const bf16x8*)&lds.s.A[p * CIP + cc * 32 + q * 8];
        }
#pragma unroll
        for (int nf = 0; nf < 4; ++nf)
          b[nf] = *(const bf16x8*)&lds.s.B[(nf * 16 + m16) * CIP + cc * 32 + q * 8];
#pragma unroll
        for (int mf = 0; mf < 2; ++mf)
#pragma unroll
          for (int nf = 0; nf < 4; ++nf)
            acc[mf][nf] = __builtin_amdgcn_mfma_f32_16x16x32_bf16(a[mf], b[nf], acc[mf][nf], 0, 0, 0);
      }
    }
  }

  const int y = y0 + wv;
  if (!NCHW_OUT) {
    // NHWC(64) bf16 direct store (internal fused1 buffer)
    u16* out = (u16*)outv;
#pragma unroll
    for (int mf = 0; mf < 2; ++mf)
#pragma unroll
      for (int nf = 0; nf < 4; ++nf)
#pragma unroll
        for (int r = 0; r < 4; ++r) {
          int px = mf * 16 + q * 4 + r;
          int x = x0 + px;
          if (x < W) {
            int co = nf * 16 + m16;
            float v = fmaxf(acc[mf][nf][r] * sc[nf] + sh[nf], 0.f);
            out[((size_t)(n * H + y) * W + x) * 64 + co] = f2bf(v);
          }
        }
  } else {
    // NCHW f32 d_out: transpose via LDS for x-contiguous stores
    float* out = (float*)outv;
    __syncthreads();                           // K-loop reads of lds.s done
    float* T = &lds.T[wv * 64 * 33];
#pragma unroll
    for (int mf = 0; mf < 2; ++mf)
#pragma unroll
      for (int nf = 0; nf < 4; ++nf)
#pragma unroll
        for (int r = 0; r < 4; ++r) {
          int px = mf * 16 + q * 4 + r;
          int co = nf * 16 + m16;
          T[co * 33 + px] = fmaxf(acc[mf][nf][r] * sc[nf] + sh[nf], 0.f);
        }
    __syncthreads();
    const int px = lane & 31, co2 = lane >> 5;
    int x = x0 + px;
#pragma unroll 4
    for (int it = 0; it < 32; ++it) {
      int co = it * 2 + co2;
      float v = T[co * 33 + px];
      if (x < W) out[((size_t)(n * 64 + co) * H + y) * W + x] = v;
    }
  }
}

// ---------------------------------------------------------------------------
extern "C" void kernel_launch(void* const* d_in, const int* in_sizes, int n_in,
                              void* d_out, int out_size, void* d_ws, size_t ws_size,
                              hipStream_t stream) {
  int I_vox[3], I_np[3], I_co[3];
  int I_w1, I_g1, I_b1, I_rm1, I_rv1, I_w2, I_g2, I_b2, I_rm2, I_rv2;
  int I_fw, I_fg, I_fb, I_fm, I_fv;
  if (in_sizes[1] == 40000) {
    I_vox[0] = 0; I_np[0] = 1; I_co[0] = 2;
    I_vox[1] = 3; I_np[1] = 4; I_co[1] = 5;
    I_vox[2] = 6; I_np[2] = 7; I_co[2] = 8;
    I_w1 = 9; I_g1 = 10; I_b1 = 11; I_rm1 = 12; I_rv1 = 13;
    I_w2 = 14; I_g2 = 15; I_b2 = 16; I_rm2 = 17; I_rv2 = 18;
    I_fw = 19; I_fg = 20; I_fb = 21; I_fm = 22; I_fv = 23;
  } else {
    I_vox[0] = 0; I_vox[1] = 1; I_vox[2] = 2;
    I_w1 = 3; I_g1 = 4; I_b1 = 5; I_rm1 = 6; I_rv1 = 7;
    I_w2 = 8; I_g2 = 9; I_b2 = 10; I_rm2 = 11; I_rv2 = 12;
    I_fw = 13; I_fg = 14; I_fb = 15; I_fm = 16; I_fv = 17;
    I_np[0] = 18; I_np[1] = 19; I_np[2] = 20;
    I_co[0] = 21; I_co[1] = 22; I_co[2] = 23;
  }

  const int HS[3] = {496, 248, 124};
  const int WS[3] = {432, 216, 108};
  int Nv[3];
  for (int s = 0; s < 3; ++s) Nv[s] = in_sizes[I_np[s]];

  char* wsp = (char*)d_ws;
  size_t off = 0;
  auto take = [&](size_t bytes) -> void* {
    void* p = wsp + off;
    off = (off + bytes + 255) & ~(size_t)255;
    return p;
  };
  float* vf[3]; int* win[3];
  for (int s = 0; s < 3; ++s) vf[s] = (float*)take((size_t)Nv[s] * 64 * 4);
  int cells[3];
  for (int s = 0; s < 3; ++s) {
    cells[s] = 4 * HS[s] * WS[s];
    win[s] = (int*)take((size_t)cells[s] * 4);
  }
  u16* buf0 = (u16*)take((size_t)cells[0] * 128 * 2);   // (4,496,432,128) NHWC bf16
  u16* buf1 = (u16*)take((size_t)cells[1] * 128 * 2);   // (4,248,216,128)
  u16* g2b  = (u16*)take((size_t)cells[2] * 64 * 2);    // (4,124,108,64)
  u16* fus1 = (u16*)take((size_t)cells[1] * 64 * 2);    // (4,248,216,64)
  u16* fwT  = (u16*)take((size_t)2 * 9 * 64 * 128 * 2);

  const float* W1 = (const float*)d_in[I_w1];
  const float* G1 = (const float*)d_in[I_g1];
  const float* B1 = (const float*)d_in[I_b1];
  const float* RM1 = (const float*)d_in[I_rm1];
  const float* RV1 = (const float*)d_in[I_rv1];
  const float* W2 = (const float*)d_in[I_w2];
  const float* G2 = (const float*)d_in[I_g2];
  const float* B2 = (const float*)d_in[I_b2];
  const float* RM2 = (const float*)d_in[I_rm2];
  const float* RV2 = (const float*)d_in[I_rv2];
  const float* FW = (const float*)d_in[I_fw];
  const float* FG = (const float*)d_in[I_fg];
  const float* FB = (const float*)d_in[I_fb];
  const float* FM = (const float*)d_in[I_fm];
  const float* FV = (const float*)d_in[I_fv];

  for (int s = 0; s < 3; ++s)
    hipMemsetAsync(win[s], 0xFF, (size_t)cells[s] * 4, stream);

  twt_kernel<<<(2 * 9 * 64 * 128 + 255) / 256, 256, 0, stream>>>(FW, fwT);

  for (int s = 0; s < 3; ++s) {
    vfe_mfma_kernel<<<512, 256, 0, stream>>>(
        (const float*)d_in[I_vox[s]], (const int*)d_in[I_np[s]],
        W1 + s * 9 * 64, G1 + s * 64, B1 + s * 64, RM1 + s * 64, RV1 + s * 64,
        W2 + s * 128 * 64, G2 + s * 64, B2 + s * 64, RM2 + s * 64, RV2 + s * 64,
        vf[s], Nv[s]);
  }
  for (int s = 0; s < 3; ++s) {
    winner_kernel<<<(Nv[s] + 255) / 256, 256, 0, stream>>>(
        (const int*)d_in[I_co[s]], win[s], Nv[s], HS[s], WS[s]);
  }
  fill_kernel<<<(cells[0] * 64 + 255) / 256, 256, 0, stream>>>(win[0], vf[0], buf0, cells[0], 128);
  fill_kernel<<<(cells[1] * 64 + 255) / 256, 256, 0, stream>>>(win[1], vf[1], buf1, cells[1], 128);
  fill_kernel<<<(cells[2] * 64 + 255) / 256, 256, 0, stream>>>(win[2], vf[2], g2b, cells[2], 64);

  {   // upsample g2 (124,108) -> buf1 ch64..127 (248,216)
    int total = cells[1] * 64;
    upsample_kernel<<<(total + 255) / 256, 256, 0, stream>>>(g2b, buf1, 124, 108, 128, 64, total);
  }
  conv_kernel<248, 216, false><<<4 * (248 / 4) * 7, 256, 0, stream>>>(
      buf1, fwT + 9 * 64 * 128, FG + 64, FB + 64, FM + 64, FV + 64, fus1);
  {   // upsample fused1 (248,216) -> buf0 ch64..127 (496,432)
    int total = cells[0] * 64;
    upsample_kernel<<<(total + 255) / 256, 256, 0, stream>>>(fus1, buf0, 248, 216, 128, 64, total);
  }
  conv_kernel<496, 432, true><<<4 * (496 / 4) * 14, 256, 0, stream>>>(
      buf0, fwT, FG, FB, FM, FV, (float*)d_out);
}

// Round 4
// 775.812 us; speedup vs baseline: 1.7571x; 1.2275x over previous
//
#include <hip/hip_runtime.h>

typedef unsigned short u16;
typedef short bf16x8 __attribute__((ext_vector_type(8)));
typedef float f32x4 __attribute__((ext_vector_type(4)));

#define EPSV 1e-3f

__device__ __forceinline__ float bf2f(u16 u) {
  union { unsigned int i; float f; } x; x.i = ((unsigned int)u) << 16; return x.f;
}
__device__ __forceinline__ u16 f2bf(float f) {
  union { float f; unsigned int i; } x; x.f = f;
  unsigned int r = x.i + 0x7fffu + ((x.i >> 16) & 1u);   // RNE
  return (u16)(r >> 16);
}

// wave-internal LDS handoff fence: drain DS pipe + stop compiler reordering
#define WAVE_FENCE() do { __builtin_amdgcn_s_waitcnt(0); __builtin_amdgcn_wave_barrier(); } while (0)

// ---------------------------------------------------------------------------
// Weight transform: fw (2,64,128,3,3) f32 -> fwT [set][ky*3+kx][co][ci] bf16
// ---------------------------------------------------------------------------
__global__ void twt_kernel(const float* __restrict__ fw, u16* __restrict__ fwT) {
  int i = blockIdx.x * blockDim.x + threadIdx.x;
  if (i >= 2 * 9 * 64 * 128) return;
  int ci = i & 127;
  int r = i >> 7;
  int co = r & 63; r >>= 6;
  int kyx = r % 9;
  int set = r / 9;
  fwT[i] = f2bf(fw[(((set * 64 + co) * 128 + ci) * 9) + kyx]);
}

// ---------------------------------------------------------------------------
// VFE via MFMA. One wave per voxel (4 waves/block, private LDS regions).
// (unchanged from round 3 — verified correct, off the critical path)
// ---------------------------------------------------------------------------
__global__ __launch_bounds__(256, 2) void vfe_mfma_kernel(
    const float* __restrict__ vox, const int* __restrict__ npts,
    const float* __restrict__ w1, const float* __restrict__ g1, const float* __restrict__ b1,
    const float* __restrict__ rm1, const float* __restrict__ rv1,
    const float* __restrict__ w2, const float* __restrict__ g2, const float* __restrict__ b2,
    const float* __restrict__ rm2, const float* __restrict__ rv2,
    float* __restrict__ vf, int N)
{
  struct PerWave {
    u16 X[32 * 72];   // h1 bf16 [t][j], stride 72
    u16 F[32 * 40];   // feat bf16 [t][k], stride 40
    u16 G[64];        // gmax1 bf16
  };
  __shared__ __align__(16) union {
    struct { u16 W1T[64 * 40]; u16 W2T[64 * 136]; } w;
    PerWave r[4];
  } lds;

  const int tid = threadIdx.x;
  const int lane = tid & 63;
  const int wv = tid >> 6;
  const int m16 = lane & 15;
  const int q = lane >> 4;

  for (int i = tid; i < 64 * 40; i += 256) {
    int c = i / 40, k = i % 40;
    lds.w.W1T[i] = f2bf(k < 9 ? w1[k * 64 + c] : 0.f);
  }
  for (int i = tid; i < 64 * 136; i += 256) {
    int c = i / 136, j = i % 136;
    lds.w.W2T[i] = f2bf(j < 128 ? w2[j * 64 + c] : 0.f);
  }
  __syncthreads();

  bf16x8 bW1[4], bLo[4][2], bHi[4][2];
  float sc1[4], sh1[4], sc2[4], sh2[4];
#pragma unroll
  for (int nf = 0; nf < 4; ++nf) {
    int c = nf * 16 + m16;
    bW1[nf] = *(const bf16x8*)&lds.w.W1T[c * 40 + q * 8];
#pragma unroll
    for (int ks = 0; ks < 2; ++ks) {
      bLo[nf][ks] = *(const bf16x8*)&lds.w.W2T[c * 136 + ks * 32 + q * 8];
      bHi[nf][ks] = *(const bf16x8*)&lds.w.W2T[c * 136 + 64 + ks * 32 + q * 8];
    }
    float s1 = g1[c] * rsqrtf(rv1[c] + EPSV);
    sc1[nf] = s1; sh1[nf] = b1[c] - rm1[c] * s1;
    float s2 = g2[c] * rsqrtf(rv2[c] + EPSV);
    sc2[nf] = s2; sh2[nf] = b2[c] - rm2[c] * s2;
  }
  __syncthreads();

  u16* X = lds.r[wv].X;
  u16* F = lds.r[wv].F;
  u16* G = lds.r[wv].G;
  for (int i = lane; i < 640; i += 64) ((unsigned int*)F)[i] = 0u;

  const int wgid = blockIdx.x * 4 + wv;
  const int wstride = gridDim.x * 4;

  for (int v = wgid; v < N; v += wstride) {
    const int n = npts[v];
    float px = 0.f, py = 0.f, pz = 0.f, pw = 0.f;
    if (lane < 32) {
      float4 u = *(const float4*)(vox + ((size_t)v * 32 + lane) * 4);
      px = u.x; py = u.y; pz = u.z; pw = u.w;
    }
    float sx = px, sy = py, sz = pz;
#pragma unroll
    for (int off = 32; off >= 1; off >>= 1) {
      sx += __shfl_xor(sx, off);
      sy += __shfl_xor(sy, off);
      sz += __shfl_xor(sz, off);
    }
    float nf_ = (float)n;
    float mx = sx / nf_, my = sy / nf_, mz = sz / nf_;
    if (lane < 32) {
      float dx = px - mx, dy = py - my, dz = pz - mz;
      bf16x8 r0, r1;
      r0[0] = (short)f2bf(px); r0[1] = (short)f2bf(py);
      r0[2] = (short)f2bf(pz); r0[3] = (short)f2bf(pw);
      r0[4] = (short)f2bf(dx); r0[5] = (short)f2bf(dy);
      r0[6] = (short)f2bf(dz); r0[7] = (short)f2bf(dx);
      r1 = (bf16x8){0, 0, 0, 0, 0, 0, 0, 0};
      r1[0] = (short)f2bf(dy);
      *(bf16x8*)&F[lane * 40 + 0] = r0;
      *(bf16x8*)&F[lane * 40 + 8] = r1;
    }
    WAVE_FENCE();

    bf16x8 a1[2];
    a1[0] = *(const bf16x8*)&F[m16 * 40 + q * 8];
    a1[1] = *(const bf16x8*)&F[(16 + m16) * 40 + q * 8];
    f32x4 acc1[2][4];
#pragma unroll
    for (int mf = 0; mf < 2; ++mf)
#pragma unroll
      for (int nf = 0; nf < 4; ++nf) {
        acc1[mf][nf] = (f32x4){0.f, 0.f, 0.f, 0.f};
        acc1[mf][nf] = __builtin_amdgcn_mfma_f32_16x16x32_bf16(a1[mf], bW1[nf], acc1[mf][nf], 0, 0, 0);
      }

    float gmx[4] = {0.f, 0.f, 0.f, 0.f};
#pragma unroll
    for (int mf = 0; mf < 2; ++mf)
#pragma unroll
      for (int nf = 0; nf < 4; ++nf)
#pragma unroll
        for (int r = 0; r < 4; ++r) {
          float h = fmaxf(acc1[mf][nf][r] * sc1[nf] + sh1[nf], 0.f);
          gmx[nf] = fmaxf(gmx[nf], h);
          int t = mf * 16 + q * 4 + r;
          X[t * 72 + nf * 16 + m16] = f2bf(h);
        }
#pragma unroll
    for (int nf = 0; nf < 4; ++nf) {
      gmx[nf] = fmaxf(gmx[nf], __shfl_xor(gmx[nf], 16));
      gmx[nf] = fmaxf(gmx[nf], __shfl_xor(gmx[nf], 32));
    }
    if (q == 0) {
#pragma unroll
      for (int nf = 0; nf < 4; ++nf) G[nf * 16 + m16] = f2bf(gmx[nf]);
    }
    WAVE_FENCE();

    f32x4 ga[4];
#pragma unroll
    for (int nf = 0; nf < 4; ++nf) ga[nf] = (f32x4){0.f, 0.f, 0.f, 0.f};
#pragma unroll
    for (int ks = 0; ks < 2; ++ks) {
      bf16x8 ag = (bf16x8){0, 0, 0, 0, 0, 0, 0, 0};
      if (m16 == 0) ag = *(const bf16x8*)&G[ks * 32 + q * 8];
#pragma unroll
      for (int nf = 0; nf < 4; ++nf)
        ga[nf] = __builtin_amdgcn_mfma_f32_16x16x32_bf16(ag, bHi[nf][ks], ga[nf], 0, 0, 0);
    }
    float gt[4];
#pragma unroll
    for (int nf = 0; nf < 4; ++nf) {
      float s = ga[nf][0] + ga[nf][1] + ga[nf][2] + ga[nf][3];
      s += __shfl_xor(s, 16);
      s += __shfl_xor(s, 32);
      gt[nf] = s;
    }

    f32x4 acc2[2][4];
#pragma unroll
    for (int mf = 0; mf < 2; ++mf)
#pragma unroll
      for (int nf = 0; nf < 4; ++nf)
        acc2[mf][nf] = (f32x4){gt[nf], gt[nf], gt[nf], gt[nf]};
#pragma unroll
    for (int ks = 0; ks < 2; ++ks) {
      bf16x8 a2[2];
      a2[0] = *(const bf16x8*)&X[m16 * 72 + ks * 32 + q * 8];
      a2[1] = *(const bf16x8*)&X[(16 + m16) * 72 + ks * 32 + q * 8];
#pragma unroll
      for (int mf = 0; mf < 2; ++mf)
#pragma unroll
        for (int nf = 0; nf < 4; ++nf)
          acc2[mf][nf] = __builtin_amdgcn_mfma_f32_16x16x32_bf16(a2[mf], bLo[nf][ks], acc2[mf][nf], 0, 0, 0);
    }

    float vm[4] = {0.f, 0.f, 0.f, 0.f};
#pragma unroll
    for (int mf = 0; mf < 2; ++mf)
#pragma unroll
      for (int nf = 0; nf < 4; ++nf)
#pragma unroll
        for (int r = 0; r < 4; ++r) {
          int t = mf * 16 + q * 4 + r;
          float h2 = fmaxf(acc2[mf][nf][r] * sc2[nf] + sh2[nf], 0.f);
          if (t < n) vm[nf] = fmaxf(vm[nf], h2);
        }
#pragma unroll
    for (int nf = 0; nf < 4; ++nf) {
      vm[nf] = fmaxf(vm[nf], __shfl_xor(vm[nf], 16));
      vm[nf] = fmaxf(vm[nf], __shfl_xor(vm[nf], 32));
    }
    float outv = (q == 0) ? vm[0] : (q == 1) ? vm[1] : (q == 2) ? vm[2] : vm[3];
    vf[(size_t)v * 64 + q * 16 + m16] = outv;
    __builtin_amdgcn_wave_barrier();
  }
}

// ---------------------------------------------------------------------------
// Scatter pass 1: last-write-wins == max voxel index per cell
// ---------------------------------------------------------------------------
__global__ void winner_kernel(const int* __restrict__ coords, int* __restrict__ win,
                              int N, int H, int W) {
  int v = blockIdx.x * blockDim.x + threadIdx.x;
  if (v >= N) return;
  int b = coords[v * 4 + 0];
  int y = min(max(coords[v * 4 + 2], 0), H - 1);
  int x = min(max(coords[v * 4 + 3], 0), W - 1);
  atomicMax(&win[(b * H + y) * W + x], v);
}

// ---------------------------------------------------------------------------
// Scatter pass 2 + zero-fill, vectorized: thread = 8 channels (16B store).
// ---------------------------------------------------------------------------
__global__ void fill_kernel(const int* __restrict__ win, const float* __restrict__ vf,
                            u16* __restrict__ dst, int cells, int cstride) {
  int i = blockIdx.x * blockDim.x + threadIdx.x;
  if (i >= cells * 8) return;
  int cell = i >> 3, c8 = (i & 7) * 8;
  int wv = win[cell];
  bf16x8 o = (bf16x8){0, 0, 0, 0, 0, 0, 0, 0};
  if (wv >= 0) {
    const float* p = vf + (size_t)wv * 64 + c8;
    float4 v0 = *(const float4*)p;
    float4 v1 = *(const float4*)(p + 4);
    o[0] = (short)f2bf(v0.x); o[1] = (short)f2bf(v0.y);
    o[2] = (short)f2bf(v0.z); o[3] = (short)f2bf(v0.w);
    o[4] = (short)f2bf(v1.x); o[5] = (short)f2bf(v1.y);
    o[6] = (short)f2bf(v1.z); o[7] = (short)f2bf(v1.w);
  }
  *(bf16x8*)&dst[(size_t)cell * cstride + c8] = o;
}

// ---------------------------------------------------------------------------
// Bilinear 2x upsample, vectorized: thread = 8 channels (16B loads/store).
// jax.image.resize half-pixel semantics -> edge-clamped taps w {0.25,0.75}.
// ---------------------------------------------------------------------------
__global__ void upsample_kernel(const u16* __restrict__ src, u16* __restrict__ dst,
                                int Hc, int Wc, int dstride, int doff, int total8) {
  int i = blockIdx.x * blockDim.x + threadIdx.x;
  if (i >= total8) return;
  int c8 = (i & 7) * 8;
  int px = i >> 3;
  int W2 = Wc * 2, H2 = Hc * 2;
  int x = px % W2; int t = px / W2; int y = t % H2; int n = t / H2;
  int ky = y >> 1, kx = x >> 1;
  int ya, yb, xa, xb; float wya, wxa;
  if ((y & 1) == 0) { ya = ky > 0 ? ky - 1 : 0; yb = ky; wya = 0.25f; }
  else              { ya = ky; yb = (ky + 1 < Hc) ? ky + 1 : Hc - 1; wya = 0.75f; }
  if ((x & 1) == 0) { xa = kx > 0 ? kx - 1 : 0; xb = kx; wxa = 0.25f; }
  else              { xa = kx; xb = (kx + 1 < Wc) ? kx + 1 : Wc - 1; wxa = 0.75f; }
  float wyb = 1.f - wya, wxb = 1.f - wxa;
  const u16* sp = src + c8;
  bf16x8 vaa = *(const bf16x8*)&sp[((size_t)(n * Hc + ya) * Wc + xa) * 64];
  bf16x8 vab = *(const bf16x8*)&sp[((size_t)(n * Hc + ya) * Wc + xb) * 64];
  bf16x8 vba = *(const bf16x8*)&sp[((size_t)(n * Hc + yb) * Wc + xa) * 64];
  bf16x8 vbb = *(const bf16x8*)&sp[((size_t)(n * Hc + yb) * Wc + xb) * 64];
  bf16x8 o;
#pragma unroll
  for (int j = 0; j < 8; ++j) {
    float v = wya * (wxa * bf2f((u16)vaa[j]) + wxb * bf2f((u16)vab[j])) +
              wyb * (wxa * bf2f((u16)vba[j]) + wxb * bf2f((u16)vbb[j]));
    o[j] = (short)f2bf(v);
  }
  *(bf16x8*)&dst[(size_t)px * dstride + doff + c8] = o;
}

// ---------------------------------------------------------------------------
// Conv3x3 + BN + ReLU, implicit GEMM with bf16 MFMA 16x16x32.
// Block: 256 thr (4 waves). Wave = 2 output rows x 32 px x 64 co -> 4x4 frags
// (M=64: 0.5 LDS reads per MFMA vs 0.75 in the M=32 version). Block covers
// 8 rows x 32 px. B (per-tap weights) double-buffered -> 1 barrier per tap.
// A halo tile: 10 rows x 34 px, staged per ci-half. LDS 67.4 KB -> 2 blk/CU.
// ---------------------------------------------------------------------------
template<int H, int W, bool NCHW_OUT>
__global__ __launch_bounds__(256, 2) void conv_kernel(
    const u16* __restrict__ in, const u16* __restrict__ wT,
    const float* __restrict__ fg, const float* __restrict__ fb,
    const float* __restrict__ fm, const float* __restrict__ fv,
    void* __restrict__ outv)
{
  constexpr int XT = 32, YT = 8;
  constexpr int XTILES = (W + XT - 1) / XT;
  constexpr int CIP = 72;                      // 64-ci half + 8 pad (u16)
  constexpr int NPX = 10 * 34;                 // halo positions
  __shared__ __align__(16) union {
    struct { u16 A[NPX * CIP]; u16 B[2][64 * CIP]; } s;
    float T[4 * 64 * 33];                      // epilogue transpose (NCHW path)
  } lds;

  const int tid = threadIdx.x;
  const int lane = tid & 63;
  const int wv = tid >> 6;                     // wave id -> rows [2wv, 2wv+1]
  const int m16 = lane & 15;
  const int q = lane >> 4;

  int bid = blockIdx.x;
  const int xt = bid % XTILES; bid /= XTILES;
  const int yt = bid % (H / YT);
  const int n = bid / (H / YT);
  const int x0 = xt * XT, y0 = yt * YT;

  float sc[4], sh[4];
#pragma unroll
  for (int nf = 0; nf < 4; ++nf) {
    int co = nf * 16 + m16;
    float s = fg[co] * rsqrtf(fv[co] + EPSV);
    sc[nf] = s;
    sh[nf] = fb[co] - fm[co] * s;
  }

  f32x4 acc[4][4];
#pragma unroll
  for (int mf = 0; mf < 4; ++mf)
#pragma unroll
    for (int nf = 0; nf < 4; ++nf)
      acc[mf][nf] = (f32x4){0.f, 0.f, 0.f, 0.f};

  for (int hf = 0; hf < 2; ++hf) {
    // stage A half: 340 halo px x 64 ci, zero-filled OOB (A protected by the
    // end-of-tap barrier of the previous hf)
    {
      const int cis = (tid & 7) * 8;
#pragma unroll
      for (int it = 0; it < 11; ++it) {
        int p = (tid >> 3) + it * 32;
        if (p < NPX) {
          int r = p / 34, xx = p - r * 34;
          int gy = y0 - 1 + r, gx = x0 - 1 + xx;
          uint4 v = make_uint4(0, 0, 0, 0);
          if (gy >= 0 && gy < H && gx >= 0 && gx < W)
            v = *(const uint4*)(in + ((size_t)((n * H + gy) * W + gx) * 128 + hf * 64 + cis));
          *(uint4*)&lds.s.A[p * CIP + cis] = v;
        }
      }
    }
    // stage B for tap 0 into buffer 0
    {
#pragma unroll
      for (int it = 0; it < 2; ++it) {
        int e8 = (it * 256 + tid) * 8;
        int co = e8 >> 6, ci = e8 & 63;
        uint4 v = *(const uint4*)(wT + (co * 128 + hf * 64 + ci));
        *(uint4*)&lds.s.B[0][co * CIP + ci] = v;
      }
    }
    __syncthreads();

    for (int kyx = 0; kyx < 9; ++kyx) {
      if (kyx < 8) {   // prefetch next tap's B into the other buffer
#pragma unroll
        for (int it = 0; it < 2; ++it) {
          int e8 = (it * 256 + tid) * 8;
          int co = e8 >> 6, ci = e8 & 63;
          uint4 v = *(const uint4*)(wT + ((kyx + 1) * 8192 + co * 128 + hf * 64 + ci));
          *(uint4*)&lds.s.B[(kyx + 1) & 1][co * CIP + ci] = v;
        }
      }
      const int ky = kyx / 3, kx = kyx - ky * 3;
      const u16* Bb = lds.s.B[kyx & 1];
#pragma unroll
      for (int cc = 0; cc < 2; ++cc) {
        bf16x8 a[4], b[4];
#pragma unroll
        for (int mf = 0; mf < 4; ++mf) {
          int p = (wv * 2 + (mf >> 1) + ky) * 34 + (mf & 1) * 16 + m16 + kx;
          a[mf] = *(const bf16x8*)&lds.s.A[p * CIP + cc * 32 + q * 8];
        }
#pragma unroll
        for (int nf = 0; nf < 4; ++nf)
          b[nf] = *(const bf16x8*)&Bb[(nf * 16 + m16) * CIP + cc * 32 + q * 8];
#pragma unroll
        for (int mf = 0; mf < 4; ++mf)
#pragma unroll
          for (int nf = 0; nf < 4; ++nf)
            acc[mf][nf] = __builtin_amdgcn_mfma_f32_16x16x32_bf16(a[mf], b[nf], acc[mf][nf], 0, 0, 0);
      }
      __syncthreads();   // B[(kyx+1)&1] visible; A/B reads of this tap done
    }
  }

  if (!NCHW_OUT) {
    // NHWC(64) bf16 direct store (internal fused1 buffer)
    u16* out = (u16*)outv;
#pragma unroll
    for (int mf = 0; mf < 4; ++mf) {
      int y = y0 + wv * 2 + (mf >> 1);
#pragma unroll
      for (int nf = 0; nf < 4; ++nf)
#pragma unroll
        for (int r = 0; r < 4; ++r) {
          int px = (mf & 1) * 16 + q * 4 + r;
          int x = x0 + px;
          if (x < W) {
            int co = nf * 16 + m16;
            float v = fmaxf(acc[mf][nf][r] * sc[nf] + sh[nf], 0.f);
            out[((size_t)(n * H + y) * W + x) * 64 + co] = f2bf(v);
          }
        }
    }
  } else {
    // NCHW f32 d_out: per-row transpose via wave-private LDS region
    float* out = (float*)outv;
    float* T = &lds.T[wv * 64 * 33];
    // final K-loop barrier already rendezvoused all waves; union reuse safe
#pragma unroll
    for (int yr = 0; yr < 2; ++yr) {
#pragma unroll
      for (int xc = 0; xc < 2; ++xc)
#pragma unroll
        for (int nf = 0; nf < 4; ++nf)
#pragma unroll
          for (int r = 0; r < 4; ++r) {
            int px = xc * 16 + q * 4 + r;
            int co = nf * 16 + m16;
            T[co * 33 + px] = fmaxf(acc[yr * 2 + xc][nf][r] * sc[nf] + sh[nf], 0.f);
          }
      WAVE_FENCE();
      const int px = lane & 31, co2 = lane >> 5;
      const int y = y0 + wv * 2 + yr;
      int x = x0 + px;
#pragma unroll 4
      for (int it = 0; it < 32; ++it) {
        int co = it * 2 + co2;
        float v = T[co * 33 + px];
        if (x < W) out[((size_t)(n * 64 + co) * H + y) * W + x] = v;
      }
      WAVE_FENCE();
    }
  }
}

// ---------------------------------------------------------------------------
extern "C" void kernel_launch(void* const* d_in, const int* in_sizes, int n_in,
                              void* d_out, int out_size, void* d_ws, size_t ws_size,
                              hipStream_t stream) {
  int I_vox[3], I_np[3], I_co[3];
  int I_w1, I_g1, I_b1, I_rm1, I_rv1, I_w2, I_g2, I_b2, I_rm2, I_rv2;
  int I_fw, I_fg, I_fb, I_fm, I_fv;
  if (in_sizes[1] == 40000) {
    I_vox[0] = 0; I_np[0] = 1; I_co[0] = 2;
    I_vox[1] = 3; I_np[1] = 4; I_co[1] = 5;
    I_vox[2] = 6; I_np[2] = 7; I_co[2] = 8;
    I_w1 = 9; I_g1 = 10; I_b1 = 11; I_rm1 = 12; I_rv1 = 13;
    I_w2 = 14; I_g2 = 15; I_b2 = 16; I_rm2 = 17; I_rv2 = 18;
    I_fw = 19; I_fg = 20; I_fb = 21; I_fm = 22; I_fv = 23;
  } else {
    I_vox[0] = 0; I_vox[1] = 1; I_vox[2] = 2;
    I_w1 = 3; I_g1 = 4; I_b1 = 5; I_rm1 = 6; I_rv1 = 7;
    I_w2 = 8; I_g2 = 9; I_b2 = 10; I_rm2 = 11; I_rv2 = 12;
    I_fw = 13; I_fg = 14; I_fb = 15; I_fm = 16; I_fv = 17;
    I_np[0] = 18; I_np[1] = 19; I_np[2] = 20;
    I_co[0] = 21; I_co[1] = 22; I_co[2] = 23;
  }

  const int HS[3] = {496, 248, 124};
  const int WS[3] = {432, 216, 108};
  int Nv[3];
  for (int s = 0; s < 3; ++s) Nv[s] = in_sizes[I_np[s]];

  char* wsp = (char*)d_ws;
  size_t off = 0;
  auto take = [&](size_t bytes) -> void* {
    void* p = wsp + off;
    off = (off + bytes + 255) & ~(size_t)255;
    return p;
  };
  float* vf[3]; int* win[3];
  for (int s = 0; s < 3; ++s) vf[s] = (float*)take((size_t)Nv[s] * 64 * 4);
  int cells[3];
  for (int s = 0; s < 3; ++s) {
    cells[s] = 4 * HS[s] * WS[s];
    win[s] = (int*)take((size_t)cells[s] * 4);
  }
  u16* buf0 = (u16*)take((size_t)cells[0] * 128 * 2);   // (4,496,432,128) NHWC bf16
  u16* buf1 = (u16*)take((size_t)cells[1] * 128 * 2);   // (4,248,216,128)
  u16* g2b  = (u16*)take((size_t)cells[2] * 64 * 2);    // (4,124,108,64)
  u16* fus1 = (u16*)take((size_t)cells[1] * 64 * 2);    // (4,248,216,64)
  u16* fwT  = (u16*)take((size_t)2 * 9 * 64 * 128 * 2);

  const float* W1 = (const float*)d_in[I_w1];
  const float* G1 = (const float*)d_in[I_g1];
  const float* B1 = (const float*)d_in[I_b1];
  const float* RM1 = (const float*)d_in[I_rm1];
  const float* RV1 = (const float*)d_in[I_rv1];
  const float* W2 = (const float*)d_in[I_w2];
  const float* G2 = (const float*)d_in[I_g2];
  const float* B2 = (const float*)d_in[I_b2];
  const float* RM2 = (const float*)d_in[I_rm2];
  const float* RV2 = (const float*)d_in[I_rv2];
  const float* FW = (const float*)d_in[I_fw];
  const float* FG = (const float*)d_in[I_fg];
  const float* FB = (const float*)d_in[I_fb];
  const float* FM = (const float*)d_in[I_fm];
  const float* FV = (const float*)d_in[I_fv];

  for (int s = 0; s < 3; ++s)
    hipMemsetAsync(win[s], 0xFF, (size_t)cells[s] * 4, stream);

  twt_kernel<<<(2 * 9 * 64 * 128 + 255) / 256, 256, 0, stream>>>(FW, fwT);

  for (int s = 0; s < 3; ++s) {
    int blocks = (Nv[s] + 3) / 4;
    if (blocks > 1024) blocks = 1024;
    vfe_mfma_kernel<<<blocks, 256, 0, stream>>>(
        (const float*)d_in[I_vox[s]], (const int*)d_in[I_np[s]],
        W1 + s * 9 * 64, G1 + s * 64, B1 + s * 64, RM1 + s * 64, RV1 + s * 64,
        W2 + s * 128 * 64, G2 + s * 64, B2 + s * 64, RM2 + s * 64, RV2 + s * 64,
        vf[s], Nv[s]);
  }
  for (int s = 0; s < 3; ++s) {
    winner_kernel<<<(Nv[s] + 255) / 256, 256, 0, stream>>>(
        (const int*)d_in[I_co[s]], win[s], Nv[s], HS[s], WS[s]);
  }
  fill_kernel<<<(cells[0] * 8 + 255) / 256, 256, 0, stream>>>(win[0], vf[0], buf0, cells[0], 128);
  fill_kernel<<<(cells[1] * 8 + 255) / 256, 256, 0, stream>>>(win[1], vf[1], buf1, cells[1], 128);
  fill_kernel<<<(cells[2] * 8 + 255) / 256, 256, 0, stream>>>(win[2], vf[2], g2b, cells[2], 64);

  {   // upsample g2 (124,108) -> buf1 ch64..127 (248,216)
    int total8 = cells[1] * 8;
    upsample_kernel<<<(total8 + 255) / 256, 256, 0, stream>>>(g2b, buf1, 124, 108, 128, 64, total8);
  }
  conv_kernel<248, 216, false><<<4 * (248 / 8) * 7, 256, 0, stream>>>(
      buf1, fwT + 9 * 64 * 128, FG + 64, FB + 64, FM + 64, FV + 64, fus1);
  {   // upsample fused1 (248,216) -> buf0 ch64..127 (496,432)
    int total8 = cells[0] * 8;
    upsample_kernel<<<(total8 + 255) / 256, 256, 0, stream>>>(fus1, buf0, 248, 216, 128, 64, total8);
  }
  conv_kernel<496, 432, true><<<4 * (496 / 8) * 14, 256, 0, stream>>>(
      buf0, fwT, FG, FB, FM, FV, (float*)d_out);
}